// Round 5
// baseline (1198.959 us; speedup 1.0000x reference)
//
#include <hip/hip_runtime.h>
#include <math.h>

#define TT 512
#define BB 128
#define OBSD 512
#define HD 256
#define PD 128
#define LD 4
#define NTB (TT*BB)   // 65536

typedef __bf16 bf16x8 __attribute__((ext_vector_type(8)));
typedef float  f32x4  __attribute__((ext_vector_type(4)));

__device__ __forceinline__ float bf2f(unsigned short u) {
    return __uint_as_float(((unsigned)u) << 16);
}
__device__ __forceinline__ unsigned short f2bf(float f) {
    unsigned u = __float_as_uint(f);
    unsigned r = (u + 0x7FFFu + ((u >> 16) & 1u)) >> 16;
    return (unsigned short)r;
}
__device__ __forceinline__ float gelu_f(float x) {
    float x3 = x * x * x;
    return 0.5f * x * (1.f + tanhf(0.7978845608028654f * (x + 0.044715f * x3)));
}

// ---- stage 128x32 bf16 tile via global_load_lds (4-wave / 256-thr block) ----
__device__ __forceinline__ void stage_tile4(const unsigned short* gbase, int ldk,
                                            int row0, int k0, unsigned short* sm, int tid)
{
    int w = tid >> 6, lane = tid & 63;
#pragma unroll
    for (int p = 0; p < 2; ++p) {
        int r = p * 64 + w * 16 + (lane >> 2);
        const unsigned short* g = gbase + (size_t)(row0 + r) * ldk + k0 + (lane & 3) * 8;
        unsigned short* l = sm + (p * 64 + w * 16) * 32;
        __builtin_amdgcn_global_load_lds(
            (const __attribute__((address_space(1))) void*)g,
            (__attribute__((address_space(3))) void*)l, 16, 0, 0);
    }
}

// ---- stage 128x32 tile, 512-thread block: one x4 load per thread -----------
__device__ __forceinline__ void stage_tile8(const unsigned short* gbase, int ldk,
                                            int row0, int k0, unsigned short* sm, int tid)
{
    int w = tid >> 6, lane = tid & 63;
    int r = w * 16 + (lane >> 2);
    const unsigned short* g = gbase + (size_t)(row0 + r) * ldk + k0 + (lane & 3) * 8;
    unsigned short* l = sm + w * 16 * 32;
    __builtin_amdgcn_global_load_lds(
        (const __attribute__((address_space(1))) void*)g,
        (__attribute__((address_space(3))) void*)l, 16, 0, 0);
}
// ---- stage 256x32 tile, 512-thread block: two x4 loads per thread ----------
__device__ __forceinline__ void stage_tile8w(const unsigned short* gbase, int ldk,
                                             int row0, int k0, unsigned short* sm, int tid)
{
    int w = tid >> 6, lane = tid & 63;
#pragma unroll
    for (int p = 0; p < 2; ++p) {
        int r = p * 128 + w * 16 + (lane >> 2);
        const unsigned short* g = gbase + (size_t)(row0 + r) * ldk + k0 + (lane & 3) * 8;
        unsigned short* l = sm + (p * 128 + w * 16) * 32;
        __builtin_amdgcn_global_load_lds(
            (const __attribute__((address_space(1))) void*)g,
            (__attribute__((address_space(3))) void*)l, 16, 0, 0);
    }
}

// ============ Fused GEMM, tile 128x256 (full N), 512 threads ================
// MODE 0 (enc1): x = leaky(acc+bias);       write X; u = LN(x)          -> U
// MODE 1 (Bu):   write bf(acc)                                          -> U
// MODE 2 (ys):   v = acc + bias[c]*aux1;    z = gelu(LN(v))             -> U
// MODE 3 (GLU):  x = Xold + aux1*sigmoid(acc+bias); write X; u = LN(x)  -> U (if wU)
template<int MODE>
__global__ __launch_bounds__(512) void mgemm2(
    const unsigned short* __restrict__ A, const unsigned short* __restrict__ BT,
    int K, const float* __restrict__ bias,
    const float* __restrict__ lnsc, const float* __restrict__ lnbi,
    const unsigned short* __restrict__ aux1, unsigned short* Xio,
    unsigned short* __restrict__ U, int wU)
{
    __shared__ unsigned short smA[128 * 32];
    __shared__ unsigned short smB[256 * 32];
    __shared__ float2 red[128][4];
    int tid = threadIdx.x;
    int lane = tid & 63, w = tid >> 6;
    int wr = w & 1, wc = w >> 1;            // wr: row half, wc: col quarter
    int m16 = lane & 15, quad = lane >> 4;
    int m0 = blockIdx.x * 128;

    f32x4 acc[4][4] = {};

    for (int k0 = 0; k0 < K; k0 += 32) {
        stage_tile8(A, K, m0, k0, smA, tid);
        stage_tile8w(BT, K, 0, k0, smB, tid);
        __syncthreads();
        bf16x8 af[4], bfr[4];
#pragma unroll
        for (int mi = 0; mi < 4; ++mi)
            af[mi] = *(const bf16x8*)(smA + (wr * 64 + mi * 16 + m16) * 32 + quad * 8);
#pragma unroll
        for (int nj = 0; nj < 4; ++nj)
            bfr[nj] = *(const bf16x8*)(smB + (wc * 64 + nj * 16 + m16) * 32 + quad * 8);
#pragma unroll
        for (int mi = 0; mi < 4; ++mi)
#pragma unroll
            for (int nj = 0; nj < 4; ++nj)
                acc[mi][nj] = __builtin_amdgcn_mfma_f32_16x16x32_bf16(
                    af[mi], bfr[nj], acc[mi][nj], 0, 0, 0);
        __syncthreads();
    }

    int colb = wc * 64 + m16;   // col for nj=0
    if (MODE == 1) {
#pragma unroll
        for (int mi = 0; mi < 4; ++mi)
#pragma unroll
            for (int nj = 0; nj < 4; ++nj)
#pragma unroll
                for (int r = 0; r < 4; ++r) {
                    int row = m0 + wr * 64 + mi * 16 + quad * 4 + r;
                    U[(size_t)row * 256 + colb + nj * 16] = f2bf(acc[mi][nj][r]);
                }
        return;
    }

    float bn[4];
#pragma unroll
    for (int nj = 0; nj < 4; ++nj) bn[nj] = bias[colb + nj * 16];

    // ---- phase 1: transform acc -> v, write X, accumulate row stats ----
#pragma unroll
    for (int mi = 0; mi < 4; ++mi) {
#pragma unroll
        for (int r = 0; r < 4; ++r) {
            int row_l = wr * 64 + mi * 16 + quad * 4 + r;
            size_t rowb = (size_t)(m0 + row_l) * 256;
            float s = 0.f, q = 0.f;
#pragma unroll
            for (int nj = 0; nj < 4; ++nj) {
                size_t idx = rowb + colb + nj * 16;
                float v = acc[mi][nj][r];
                if (MODE == 0) {
                    v += bn[nj]; v = v > 0.f ? v : 0.01f * v;
                    Xio[idx] = f2bf(v);
                } else if (MODE == 2) {
                    v += bn[nj] * bf2f(aux1[idx]);
                } else if (MODE == 3) {
                    float sg = 1.f / (1.f + expf(-(v + bn[nj])));
                    v = bf2f(Xio[idx]) + bf2f(aux1[idx]) * sg;
                    Xio[idx] = f2bf(v);
                }
                acc[mi][nj][r] = v;
                s += v; q += v * v;
            }
            if (MODE != 3 || wU) {
#pragma unroll
                for (int mask = 1; mask < 16; mask <<= 1) {
                    s += __shfl_xor(s, mask);
                    q += __shfl_xor(q, mask);
                }
                if (m16 == 0) red[row_l][wc] = float2{s, q};
            }
        }
    }
    if (MODE == 3 && !wU) return;
    __syncthreads();

    // ---- phase 2: finalize LN, write U ----
    float ls[4], lb[4];
#pragma unroll
    for (int nj = 0; nj < 4; ++nj) { ls[nj] = lnsc[colb + nj * 16]; lb[nj] = lnbi[colb + nj * 16]; }
#pragma unroll
    for (int mi = 0; mi < 4; ++mi) {
#pragma unroll
        for (int r = 0; r < 4; ++r) {
            int row_l = wr * 64 + mi * 16 + quad * 4 + r;
            float2 t0 = red[row_l][0], t1 = red[row_l][1], t2 = red[row_l][2], t3 = red[row_l][3];
            float S = t0.x + t1.x + t2.x + t3.x;
            float Q = t0.y + t1.y + t2.y + t3.y;
            float mu = S * (1.f / 256.f);
            float var = Q * (1.f / 256.f) - mu * mu;
            float rstd = rsqrtf(var + 1e-6f);
            size_t rowb = (size_t)(m0 + row_l) * 256;
#pragma unroll
            for (int nj = 0; nj < 4; ++nj) {
                float o = (acc[mi][nj][r] - mu) * rstd * ls[nj] + lb[nj];
                if (MODE == 2) o = gelu_f(o);
                U[rowb + colb + nj * 16] = f2bf(o);
            }
        }
    }
}

// ============ Plain GEMM 128x128 tile (N=128 GEMMs): leaky(acc+bias) ========
__global__ __launch_bounds__(256) void mgemm(
    const unsigned short* __restrict__ A, const unsigned short* __restrict__ BT,
    unsigned short* __restrict__ C, int M, int N, int K,
    const float* __restrict__ bias)
{
    __shared__ unsigned short smA[128 * 32];
    __shared__ unsigned short smB[128 * 32];
    int tid = threadIdx.x;
    int lane = tid & 63, w = tid >> 6;
    int wr = w & 1, wc = w >> 1;
    int m16 = lane & 15, quad = lane >> 4;
    int m0 = blockIdx.x * 128, n0 = blockIdx.y * 128;

    f32x4 acc[4][4] = {};
    for (int k0 = 0; k0 < K; k0 += 32) {
        stage_tile4(A, K, m0, k0, smA, tid);
        stage_tile4(BT, K, n0, k0, smB, tid);
        __syncthreads();
        bf16x8 af[4], bfr[4];
#pragma unroll
        for (int mi = 0; mi < 4; ++mi)
            af[mi] = *(const bf16x8*)(smA + (wr * 64 + mi * 16 + m16) * 32 + quad * 8);
#pragma unroll
        for (int nj = 0; nj < 4; ++nj)
            bfr[nj] = *(const bf16x8*)(smB + (wc * 64 + nj * 16 + m16) * 32 + quad * 8);
#pragma unroll
        for (int mi = 0; mi < 4; ++mi)
#pragma unroll
            for (int nj = 0; nj < 4; ++nj)
                acc[mi][nj] = __builtin_amdgcn_mfma_f32_16x16x32_bf16(
                    af[mi], bfr[nj], acc[mi][nj], 0, 0, 0);
        __syncthreads();
    }
#pragma unroll
    for (int mi = 0; mi < 4; ++mi)
#pragma unroll
        for (int nj = 0; nj < 4; ++nj) {
            int mg = m0 + wr * 64 + mi * 16 + quad * 4;
            int ng = n0 + wc * 64 + nj * 16 + m16;
            float bv = bias[ng];
#pragma unroll
            for (int r = 0; r < 4; ++r) {
                float v = acc[mi][nj][r] + bv;
                v = v > 0.f ? v : 0.01f * v;
                C[(size_t)(mg + r) * N + ng] = f2bf(v);
            }
        }
}

// ======= enc0 GEMM: A is f32 (obs), staged to bf16 LDS in-kernel ============
__global__ __launch_bounds__(256) void mgemm_obs(
    const float* __restrict__ A, const unsigned short* __restrict__ BT,
    unsigned short* __restrict__ C, int M, int N, int K,
    const float* __restrict__ bias)
{
    __shared__ unsigned short smA[128 * 32];
    __shared__ unsigned short smB[128 * 32];
    int tid = threadIdx.x;
    int lane = tid & 63, w = tid >> 6;
    int wr = w & 1, wc = w >> 1;
    int m16 = lane & 15, quad = lane >> 4;
    int m0 = blockIdx.x * 128, n0 = blockIdx.y * 128;

    f32x4 acc[4][4] = {};
    for (int k0 = 0; k0 < K; k0 += 32) {
        // A: 128 rows x 32 k f32 -> bf16 LDS. 1024 float4 loads, 4/thread.
#pragma unroll
        for (int it = 0; it < 4; ++it) {
            int idx = it * 256 + tid;
            int r = idx >> 3, kq = (idx & 7) * 4;
            float4 v = *(const float4*)(A + (size_t)(m0 + r) * K + k0 + kq);
            ushort4 o = { f2bf(v.x), f2bf(v.y), f2bf(v.z), f2bf(v.w) };
            *(ushort4*)(smA + r * 32 + kq) = o;
        }
        stage_tile4(BT, K, n0, k0, smB, tid);
        __syncthreads();
        bf16x8 af[4], bfr[4];
#pragma unroll
        for (int mi = 0; mi < 4; ++mi)
            af[mi] = *(const bf16x8*)(smA + (wr * 64 + mi * 16 + m16) * 32 + quad * 8);
#pragma unroll
        for (int nj = 0; nj < 4; ++nj)
            bfr[nj] = *(const bf16x8*)(smB + (wc * 64 + nj * 16 + m16) * 32 + quad * 8);
#pragma unroll
        for (int mi = 0; mi < 4; ++mi)
#pragma unroll
            for (int nj = 0; nj < 4; ++nj)
                acc[mi][nj] = __builtin_amdgcn_mfma_f32_16x16x32_bf16(
                    af[mi], bfr[nj], acc[mi][nj], 0, 0, 0);
        __syncthreads();
    }
#pragma unroll
    for (int mi = 0; mi < 4; ++mi)
#pragma unroll
        for (int nj = 0; nj < 4; ++nj) {
            int mg = m0 + wr * 64 + mi * 16 + quad * 4;
            int ng = n0 + wc * 64 + nj * 16 + m16;
            float bv = bias[ng];
#pragma unroll
            for (int r = 0; r < 4; ++r) {
                float v = acc[mi][nj][r] + bv;
                v = v > 0.f ? v : 0.01f * v;
                C[(size_t)(mg + r) * N + ng] = f2bf(v);
            }
        }
}

// ------------- Chunk-parallel scan, interleaved (re,im) packing -------------
// BU/XS rows: col 2p = re(p), col 2p+1 = im(p). Block=(b,ph); lane owns one p;
// one uint load+store per t-step -> 256B contiguous per wave access.
__global__ __launch_bounds__(512) void scan2_k(
    const unsigned short* __restrict__ bu, unsigned short* __restrict__ xs,
    const float* __restrict__ dones,
    const float* __restrict__ h0re, const float* __restrict__ h0im,
    const float* __restrict__ lamre, const float* __restrict__ lamim,
    const float* __restrict__ lstep,
    float* __restrict__ outre, float* __restrict__ outim)
{
    __shared__ float sdone[TT];
    __shared__ float4 ssum[8][64];
    __shared__ float2 shin[8][64];
    int tid = threadIdx.x;
    int b  = blockIdx.x >> 1;
    int ph = blockIdx.x & 1;
    int chunk = tid >> 6, pl = tid & 63;
    int p = ph * 64 + pl;
    sdone[tid] = dones[tid * BB + b];
    float lr = lamre[p], li = lamim[p];
    float st = expf(lstep[p]);
    float er = expf(lr * st);
    float ar = er * cosf(li * st);
    float ai = er * sinf(li * st);
    __syncthreads();

    int t0 = chunk * 64;
    unsigned buf[64];
    float Ar = 1.f, Ai = 0.f, br = 0.f, bi = 0.f;
#pragma unroll
    for (int j = 0; j < 64; ++j) {
        size_t off = ((size_t)(t0 + j) * BB + b) * 256 + 2 * p;
        unsigned v = *(const unsigned*)(bu + off);
        buf[j] = v;
        float bur = bf2f((unsigned short)(v & 0xFFFFu));
        float bui = bf2f((unsigned short)(v >> 16));
        if (sdone[t0 + j] != 0.f) {
            Ar = 0.f; Ai = 0.f; br = bur; bi = bui;
        } else {
            float nAr = ar * Ar - ai * Ai;
            float nAi = ar * Ai + ai * Ar;
            float nbr = fmaf(ar, br, fmaf(-ai, bi, bur));
            float nbi = fmaf(ar, bi, fmaf(ai, br, bui));
            Ar = nAr; Ai = nAi; br = nbr; bi = nbi;
        }
    }
    ssum[chunk][pl] = float4{Ar, Ai, br, bi};
    __syncthreads();
    if (tid < 64) {
        int gid = b * 128 + p;
        float hr = h0re[gid], hi = h0im[gid];
#pragma unroll
        for (int c = 0; c < 8; ++c) {
            shin[c][pl] = float2{hr, hi};
            float4 s = ssum[c][pl];
            float nhr = fmaf(s.x, hr, fmaf(-s.y, hi, s.z));
            float nhi = fmaf(s.x, hi, fmaf(s.y, hr, s.w));
            hr = nhr; hi = nhi;
        }
        outre[gid] = hr; outim[gid] = hi;
    }
    __syncthreads();
    float hr = shin[chunk][pl].x, hi = shin[chunk][pl].y;
#pragma unroll
    for (int j = 0; j < 64; ++j) {
        unsigned v = buf[j];
        float bur = bf2f((unsigned short)(v & 0xFFFFu));
        float bui = bf2f((unsigned short)(v >> 16));
        float nr, ni;
        if (sdone[t0 + j] != 0.f) { nr = bur; ni = bui; }
        else {
            nr = fmaf(ar, hr, fmaf(-ai, hi, bur));
            ni = fmaf(ar, hi, fmaf(ai, hr, bui));
        }
        hr = nr; hi = ni;
        size_t off = ((size_t)(t0 + j) * BB + b) * 256 + 2 * p;
        *(unsigned*)(xs + off) = ((unsigned)f2bf(ni) << 16) | f2bf(nr);
    }
}

// -- Precompute B_barT (interleaved n: 2p/2p+1) and CcatT (interleaved k) ----
__global__ __launch_bounds__(256) void prep_k(
    const float* __restrict__ Br, const float* __restrict__ Bi,
    const float* __restrict__ Cr, const float* __restrict__ Ci,
    const float* __restrict__ Lr, const float* __restrict__ Li,
    const float* __restrict__ ls, unsigned short* bbarT, unsigned short* ccatT)
{
    int gid = blockIdx.x * 256 + threadIdx.x;   // L*P*H = 131072
    int l = gid >> 15;
    int rem = gid & 32767;
    int p = rem >> 8;
    int h = rem & 255;
    float lr = Lr[l * PD + p], li = Li[l * PD + p];
    float st = expf(ls[l * PD + p]);
    float er = expf(lr * st);
    float lbr = er * cosf(li * st);
    float lbi = er * sinf(li * st);
    float nr = lbr - 1.f, ni = lbi;
    float den = lr * lr + li * li;
    float fr = (nr * lr + ni * li) / den;
    float fi = (ni * lr - nr * li) / den;
    float bre = Br[(size_t)(l * PD + p) * HD + h];
    float bim = Bi[(size_t)(l * PD + p) * HD + h];
    size_t lb = (size_t)l * 65536;
    bbarT[lb + (size_t)(2 * p) * 256 + h]     = f2bf(fr * bre - fi * bim);
    bbarT[lb + (size_t)(2 * p + 1) * 256 + h] = f2bf(fr * bim + fi * bre);
    float cre = Cr[(size_t)(l * HD + h) * PD + p];
    float cim = Ci[(size_t)(l * HD + h) * PD + p];
    ccatT[lb + (size_t)h * 256 + 2 * p]     = f2bf(2.f * cre);
    ccatT[lb + (size_t)h * 256 + 2 * p + 1] = f2bf(-2.f * cim);
}

// -------- transpose+convert: in f32 [K][N] -> out bf16 [N][K] ---------------
__global__ __launch_bounds__(256) void tcvt_k(const float* __restrict__ in,
    unsigned short* __restrict__ out, int K, int N)
{
    int gid = blockIdx.x * 256 + threadIdx.x;
    if (gid >= K * N) return;
    int k = gid / N, n = gid - k * N;
    out[(size_t)n * K + k] = f2bf(in[gid]);
}

// ---------------- Final heads: wave per row -> out[row*9 + ...] -------------
__global__ __launch_bounds__(256) void head_k(
    const unsigned short* __restrict__ am2, const unsigned short* __restrict__ v2,
    const float* __restrict__ adW, const float* __restrict__ adb,
    const float* __restrict__ lstd,
    const float* __restrict__ vdW, const float* __restrict__ vdb,
    float* out)
{
    int wid = threadIdx.x >> 6, lane = threadIdx.x & 63;
    size_t row = (size_t)blockIdx.x * 4 + wid;
    float a1 = bf2f(am2[row * 128 + lane]);
    float a2 = bf2f(am2[row * 128 + 64 + lane]);
    float w1 = bf2f(v2[row * 128 + lane]);
    float w2 = bf2f(v2[row * 128 + 64 + lane]);
    float vals[5];
#pragma unroll
    for (int a = 0; a < 4; ++a)
        vals[a] = a1 * adW[lane * 4 + a] + a2 * adW[(lane + 64) * 4 + a];
    vals[4] = w1 * vdW[lane] + w2 * vdW[64 + lane];
#pragma unroll
    for (int off = 32; off; off >>= 1)
#pragma unroll
        for (int k = 0; k < 5; ++k) vals[k] += __shfl_xor(vals[k], off);
    if (lane == 0) {
        size_t o = row * 9;
#pragma unroll
        for (int a = 0; a < 4; ++a) out[o + a] = vals[a] + adb[a];
#pragma unroll
        for (int a = 0; a < 4; ++a) out[o + 4 + a] = expf(lstd[a]);
        out[o + 8] = vals[4] + vdb[0];
    }
}

extern "C" void kernel_launch(void* const* d_in, const int* in_sizes, int n_in,
                              void* d_out, int out_size, void* d_ws, size_t ws_size,
                              hipStream_t stream) {
    (void)in_sizes; (void)n_in; (void)out_size; (void)ws_size;
    const float* obs     = (const float*)d_in[0];
    const float* dones   = (const float*)d_in[1];
    const float* hre     = (const float*)d_in[2];
    const float* him     = (const float*)d_in[3];
    const float* enc0_W  = (const float*)d_in[4];
    const float* enc0_b  = (const float*)d_in[5];
    const float* enc1_W  = (const float*)d_in[6];
    const float* enc1_b  = (const float*)d_in[7];
    const float* nsc     = (const float*)d_in[8];
    const float* nbi     = (const float*)d_in[9];
    const float* Lre     = (const float*)d_in[10];
    const float* Lim     = (const float*)d_in[11];
    const float* B_re    = (const float*)d_in[12];
    const float* B_im    = (const float*)d_in[13];
    const float* C_re    = (const float*)d_in[14];
    const float* C_im    = (const float*)d_in[15];
    const float* Dv      = (const float*)d_in[16];
    const float* lstep   = (const float*)d_in[17];
    const float* glu_W   = (const float*)d_in[18];
    const float* glu_b   = (const float*)d_in[19];
    const float* ab0_W   = (const float*)d_in[20];
    const float* ab0_b   = (const float*)d_in[21];
    const float* ab1_W   = (const float*)d_in[22];
    const float* ab1_b   = (const float*)d_in[23];
    const float* adec_W  = (const float*)d_in[24];
    const float* adec_b  = (const float*)d_in[25];
    const float* log_std = (const float*)d_in[26];
    const float* vb0_W   = (const float*)d_in[27];
    const float* vb0_b   = (const float*)d_in[28];
    const float* vb1_W   = (const float*)d_in[29];
    const float* vb1_b   = (const float*)d_in[30];
    const float* vdec_W  = (const float*)d_in[31];
    const float* vdec_b  = (const float*)d_in[32];

    const size_t MB = (size_t)1 << 20;
    char* wsb = (char*)d_ws;
    unsigned short* XS    = (unsigned short*)(wsb);              // 32MB (per-layer xs)
    unsigned short* AM1   = (unsigned short*)(wsb);              // 16MB (heads)
    unsigned short* V1    = (unsigned short*)(wsb + 16 * MB);    // 16MB (heads)
    unsigned short* AM2   = (unsigned short*)(wsb + 32 * MB);    // 16MB (heads)
    unsigned short* V2    = (unsigned short*)(wsb + 48 * MB);    // 16MB (heads)
    unsigned short* U1    = (unsigned short*)(wsb + 64 * MB);    // 16MB (enc0 out)
    unsigned short* X     = (unsigned short*)(wsb + 96 * MB);    // 32MB residual bf16
    unsigned short* U     = (unsigned short*)(wsb + 128 * MB);   // 32MB (u / z)
    unsigned short* BU    = (unsigned short*)(wsb + 160 * MB);   // 32MB (Bu)
    char* wgt = wsb + 192 * MB;
    unsigned short* BBART = (unsigned short*)(wgt);              // 512KB
    unsigned short* CCATT = (unsigned short*)(wgt + 512 * 1024);
    unsigned short* GLUT  = (unsigned short*)(wgt + 1024 * 1024);
    unsigned short* E0T   = (unsigned short*)(wgt + 1536 * 1024);
    unsigned short* E1T   = (unsigned short*)(wgt + 1664 * 1024);
    unsigned short* AB0T  = (unsigned short*)(wgt + 1728 * 1024);
    unsigned short* AB1T  = (unsigned short*)(wgt + 1792 * 1024);
    unsigned short* VB0T  = (unsigned short*)(wgt + 1824 * 1024);
    unsigned short* VB1T  = (unsigned short*)(wgt + 1888 * 1024);

    float* out   = (float*)d_out;
    float* outre = out + (size_t)NTB * 9;
    float* outim = outre + LD * BB * PD;

    // ---- weight prep ----
    prep_k<<<512, 256, 0, stream>>>(B_re, B_im, C_re, C_im, Lre, Lim, lstep, BBART, CCATT);
    tcvt_k<<<256, 256, 0, stream>>>(enc0_W, E0T, 512, 128);
    tcvt_k<<<128, 256, 0, stream>>>(enc1_W, E1T, 128, 256);
    for (int l = 0; l < LD; ++l)
        tcvt_k<<<256, 256, 0, stream>>>(glu_W + (size_t)l * 65536, GLUT + (size_t)l * 65536, 256, 256);
    tcvt_k<<<128, 256, 0, stream>>>(ab0_W, AB0T, 256, 128);
    tcvt_k<<<64, 256, 0, stream>>>(ab1_W, AB1T, 128, 128);
    tcvt_k<<<128, 256, 0, stream>>>(vb0_W, VB0T, 256, 128);
    tcvt_k<<<64, 256, 0, stream>>>(vb1_W, VB1T, 128, 128);

    // ---- encoder ----
    mgemm_obs<<<dim3(512, 1), 256, 0, stream>>>(obs, E0T, U1, NTB, 128, 512, enc0_b);
    // enc1 fused: X = leaky(U1@E1+b), U = LN_0(X)
    mgemm2<0><<<512, 512, 0, stream>>>(U1, E1T, 128, enc1_b, nsc, nbi, nullptr, X, U, 1);

    // ---- S5 layers ----
    for (int l = 0; l < LD; ++l) {
        mgemm2<1><<<512, 512, 0, stream>>>(U, BBART + (size_t)l * 65536, 256,
                                           nullptr, nullptr, nullptr, nullptr, nullptr, BU, 0);
        scan2_k<<<256, 512, 0, stream>>>(BU, XS, dones, hre + l * BB * PD, him + l * BB * PD,
                                         Lre + l * PD, Lim + l * PD, lstep + l * PD,
                                         outre + l * BB * PD, outim + l * BB * PD);
        // z = gelu(LN_l(xs@C + D*u))   (in-place U: aux1=U read, U written)
        mgemm2<2><<<512, 512, 0, stream>>>(XS, CCATT + (size_t)l * 65536, 256,
                                           Dv + l * HD, nsc + l * HD, nbi + l * HD, U, nullptr, U, 1);
        // x += z*sigmoid(z@W+b); u_next = LN_{l+1}(x)  (skip LN on last layer)
        const float* nsc2 = nsc + ((l + 1 < LD) ? (l + 1) * HD : 0);
        const float* nbi2 = nbi + ((l + 1 < LD) ? (l + 1) * HD : 0);
        mgemm2<3><<<512, 512, 0, stream>>>(U, GLUT + (size_t)l * 65536, 256,
                                           glu_b + l * HD, nsc2, nbi2, U, X, U, (l + 1 < LD) ? 1 : 0);
    }

    // ---- heads ----
    mgemm<<<dim3(512, 1), 256, 0, stream>>>(X, AB0T, AM1, NTB, 128, 256, ab0_b);
    mgemm<<<dim3(512, 1), 256, 0, stream>>>(AM1, AB1T, AM2, NTB, 128, 128, ab1_b);
    mgemm<<<dim3(512, 1), 256, 0, stream>>>(X, VB0T, V1, NTB, 128, 256, vb0_b);
    mgemm<<<dim3(512, 1), 256, 0, stream>>>(V1, VB1T, V2, NTB, 128, 128, vb1_b);
    head_k<<<NTB / 4, 256, 0, stream>>>(AM2, V2, adec_W, adec_b, log_std, vdec_W, vdec_b, out);
}

// Round 6
// 984.695 us; speedup vs baseline: 1.2176x; 1.2176x over previous
//
#include <hip/hip_runtime.h>
#include <math.h>

#define TT 512
#define BB 128
#define OBSD 512
#define HD 256
#define PD 128
#define LD 4
#define NTB (TT*BB)   // 65536

typedef __bf16 bf16x8 __attribute__((ext_vector_type(8)));
typedef float  f32x4  __attribute__((ext_vector_type(4)));

__device__ __forceinline__ float bf2f(unsigned short u) {
    return __uint_as_float(((unsigned)u) << 16);
}
__device__ __forceinline__ unsigned short f2bf(float f) {
    unsigned u = __float_as_uint(f);
    unsigned r = (u + 0x7FFFu + ((u >> 16) & 1u)) >> 16;
    return (unsigned short)r;
}
__device__ __forceinline__ float gelu_f(float x) {
    float x3 = x * x * x;
    return 0.5f * x * (1.f + tanhf(0.7978845608028654f * (x + 0.044715f * x3)));
}

// ============ Fused GEMM, tile 64 x (NJ*64), 256 threads, transposed MFMA ===
// acc[mi][nj][r] = C[row = mi*16 + (lane&15)][col = w*NJ*16 + nj*16 + quad*4 + r]
// MODE 0 (enc1): x = leaky(acc+bias);  write X; u = LN(x)           -> U
// MODE 1 (Bu):   write bf(acc)                                      -> U
// MODE 2 (ys):   v = acc + bias[c]*aux1; z = gelu(LN(v))            -> U
// MODE 3 (GLU):  x = Xold + aux1*sigmoid(acc+bias); write X; LN->U if wU
// MODE 4 (head): leaky(acc+bias)                                    -> U
template<int MODE, int NJ>
__global__ __launch_bounds__(256) void mgemm2(
    const unsigned short* __restrict__ A, const unsigned short* __restrict__ BT,
    int K, const float* __restrict__ bias,
    const float* __restrict__ lnsc, const float* __restrict__ lnbi,
    const unsigned short* __restrict__ aux1, unsigned short* Xio,
    unsigned short* __restrict__ U, int wU)
{
    const int N = NJ * 64;
    __shared__ unsigned short smA[64 * 32];
    __shared__ unsigned short smB[NJ * 64 * 32];
    __shared__ float2 red[64][4];
    int tid = threadIdx.x;
    int lane = tid & 63, w = tid >> 6;
    int m16 = lane & 15, quad = lane >> 4;
    int m0 = blockIdx.x * 64;

    f32x4 acc[4][NJ] = {};

    for (int k0 = 0; k0 < K; k0 += 32) {
        // A: 64x32, one 16B load per thread
        {
            const unsigned short* g = A + (size_t)(m0 + (tid >> 2)) * K + k0 + (tid & 3) * 8;
            unsigned short* l = smA + tid * 8;
            __builtin_amdgcn_global_load_lds(
                (const __attribute__((address_space(1))) void*)g,
                (__attribute__((address_space(3))) void*)l, 16, 0, 0);
        }
        // B: (NJ*64)x32, NJ 16B loads per thread
#pragma unroll
        for (int p = 0; p < NJ; ++p) {
            const unsigned short* g = BT + (size_t)(p * 64 + (tid >> 2)) * K + k0 + (tid & 3) * 8;
            unsigned short* l = smB + p * 2048 + tid * 8;
            __builtin_amdgcn_global_load_lds(
                (const __attribute__((address_space(1))) void*)g,
                (__attribute__((address_space(3))) void*)l, 16, 0, 0);
        }
        __syncthreads();
        bf16x8 af[4], bfr[NJ];
#pragma unroll
        for (int mi = 0; mi < 4; ++mi)
            af[mi] = *(const bf16x8*)(smA + (mi * 16 + m16) * 32 + quad * 8);
#pragma unroll
        for (int nj = 0; nj < NJ; ++nj)
            bfr[nj] = *(const bf16x8*)(smB + (w * NJ * 16 + nj * 16 + m16) * 32 + quad * 8);
#pragma unroll
        for (int mi = 0; mi < 4; ++mi)
#pragma unroll
            for (int nj = 0; nj < NJ; ++nj)
                acc[mi][nj] = __builtin_amdgcn_mfma_f32_16x16x32_bf16(
                    bfr[nj], af[mi], acc[mi][nj], 0, 0, 0);   // transposed: C^T
        __syncthreads();
    }

    int colb = w * NJ * 16 + quad * 4;    // + nj*16

    if (MODE == 1) {
#pragma unroll
        for (int mi = 0; mi < 4; ++mi) {
            size_t rowb = (size_t)(m0 + mi * 16 + m16) * N;
#pragma unroll
            for (int nj = 0; nj < NJ; ++nj) {
                ushort4 o = { f2bf(acc[mi][nj][0]), f2bf(acc[mi][nj][1]),
                              f2bf(acc[mi][nj][2]), f2bf(acc[mi][nj][3]) };
                *(ushort4*)(U + rowb + colb + nj * 16) = o;
            }
        }
        return;
    }

    float4 bn[NJ];
#pragma unroll
    for (int nj = 0; nj < NJ; ++nj) bn[nj] = *(const float4*)(bias + colb + nj * 16);

    // ---- phase 1: transform acc -> v, write X/U, accumulate row stats ----
#pragma unroll
    for (int mi = 0; mi < 4; ++mi) {
        size_t rowb = (size_t)(m0 + mi * 16 + m16) * N;
        float s = 0.f, q = 0.f;
#pragma unroll
        for (int nj = 0; nj < NJ; ++nj) {
            ushort4 a1, xo;
            if (MODE == 2 || MODE == 3) a1 = *(const ushort4*)(aux1 + rowb + colb + nj * 16);
            if (MODE == 3)              xo = *(const ushort4*)(Xio + rowb + colb + nj * 16);
            float vv[4];
#pragma unroll
            for (int r = 0; r < 4; ++r) {
                float v = acc[mi][nj][r];
                float bv = (r == 0) ? bn[nj].x : (r == 1) ? bn[nj].y : (r == 2) ? bn[nj].z : bn[nj].w;
                if (MODE == 0 || MODE == 4) {
                    v += bv; v = v > 0.f ? v : 0.01f * v;
                } else if (MODE == 2) {
                    float u = bf2f(r == 0 ? a1.x : r == 1 ? a1.y : r == 2 ? a1.z : a1.w);
                    v += bv * u;
                } else if (MODE == 3) {
                    float zz = bf2f(r == 0 ? a1.x : r == 1 ? a1.y : r == 2 ? a1.z : a1.w);
                    float xx = bf2f(r == 0 ? xo.x : r == 1 ? xo.y : r == 2 ? xo.z : xo.w);
                    float sg = 1.f / (1.f + expf(-(v + bv)));
                    v = xx + zz * sg;
                }
                vv[r] = v;
                acc[mi][nj][r] = v;
                s += v; q += v * v;
            }
            if (MODE == 0 || MODE == 3) {
                ushort4 o = { f2bf(vv[0]), f2bf(vv[1]), f2bf(vv[2]), f2bf(vv[3]) };
                *(ushort4*)(Xio + rowb + colb + nj * 16) = o;
            } else if (MODE == 4) {
                ushort4 o = { f2bf(vv[0]), f2bf(vv[1]), f2bf(vv[2]), f2bf(vv[3]) };
                *(ushort4*)(U + rowb + colb + nj * 16) = o;
            }
        }
        if (MODE != 4 && (MODE != 3 || wU)) {
            s += __shfl_xor(s, 16); q += __shfl_xor(q, 16);
            s += __shfl_xor(s, 32); q += __shfl_xor(q, 32);
            if (quad == 0) red[mi * 16 + m16][w] = float2{s, q};
        }
    }
    if (MODE == 4 || (MODE == 3 && !wU)) return;
    __syncthreads();

    // ---- phase 2: finalize LN, write U ----
    float4 ls[NJ], lb[NJ];
#pragma unroll
    for (int nj = 0; nj < NJ; ++nj) {
        ls[nj] = *(const float4*)(lnsc + colb + nj * 16);
        lb[nj] = *(const float4*)(lnbi + colb + nj * 16);
    }
#pragma unroll
    for (int mi = 0; mi < 4; ++mi) {
        int row_l = mi * 16 + m16;
        float2 t0 = red[row_l][0], t1 = red[row_l][1], t2 = red[row_l][2], t3 = red[row_l][3];
        float S = t0.x + t1.x + t2.x + t3.x;
        float Q = t0.y + t1.y + t2.y + t3.y;
        float mu = S * (1.f / 256.f);
        float var = Q * (1.f / 256.f) - mu * mu;
        float rstd = rsqrtf(var + 1e-6f);
        size_t rowb = (size_t)(m0 + row_l) * N;
#pragma unroll
        for (int nj = 0; nj < NJ; ++nj) {
            float o[4];
#pragma unroll
            for (int r = 0; r < 4; ++r) {
                float sc = (r == 0) ? ls[nj].x : (r == 1) ? ls[nj].y : (r == 2) ? ls[nj].z : ls[nj].w;
                float bi = (r == 0) ? lb[nj].x : (r == 1) ? lb[nj].y : (r == 2) ? lb[nj].z : lb[nj].w;
                float v = (acc[mi][nj][r] - mu) * rstd * sc + bi;
                if (MODE == 2) v = gelu_f(v);
                o[r] = v;
            }
            ushort4 ov = { f2bf(o[0]), f2bf(o[1]), f2bf(o[2]), f2bf(o[3]) };
            *(ushort4*)(U + rowb + colb + nj * 16) = ov;
        }
    }
}

// ======= enc0: A f32 (obs), staged to bf16 LDS in VGPRs; tile 64x128 ========
__global__ __launch_bounds__(256) void mgemm_obs(
    const float* __restrict__ A, const unsigned short* __restrict__ BT,
    unsigned short* __restrict__ U, const float* __restrict__ bias)
{
    const int K = 512, NJ = 2, N = 128;
    __shared__ unsigned short smA[64 * 32];
    __shared__ unsigned short smB[NJ * 64 * 32];
    int tid = threadIdx.x;
    int lane = tid & 63, w = tid >> 6;
    int m16 = lane & 15, quad = lane >> 4;
    int m0 = blockIdx.x * 64;

    f32x4 acc[4][NJ] = {};
    for (int k0 = 0; k0 < K; k0 += 32) {
#pragma unroll
        for (int p = 0; p < 2; ++p) {
            int idx = p * 256 + tid;
            int r = idx >> 3, kq = (idx & 7) * 4;
            float4 v = *(const float4*)(A + (size_t)(m0 + r) * K + k0 + kq);
            ushort4 o = { f2bf(v.x), f2bf(v.y), f2bf(v.z), f2bf(v.w) };
            *(ushort4*)(smA + r * 32 + kq) = o;
        }
#pragma unroll
        for (int p = 0; p < NJ; ++p) {
            const unsigned short* g = BT + (size_t)(p * 64 + (tid >> 2)) * K + k0 + (tid & 3) * 8;
            unsigned short* l = smB + p * 2048 + tid * 8;
            __builtin_amdgcn_global_load_lds(
                (const __attribute__((address_space(1))) void*)g,
                (__attribute__((address_space(3))) void*)l, 16, 0, 0);
        }
        __syncthreads();
        bf16x8 af[4], bfr[NJ];
#pragma unroll
        for (int mi = 0; mi < 4; ++mi)
            af[mi] = *(const bf16x8*)(smA + (mi * 16 + m16) * 32 + quad * 8);
#pragma unroll
        for (int nj = 0; nj < NJ; ++nj)
            bfr[nj] = *(const bf16x8*)(smB + (w * NJ * 16 + nj * 16 + m16) * 32 + quad * 8);
#pragma unroll
        for (int mi = 0; mi < 4; ++mi)
#pragma unroll
            for (int nj = 0; nj < NJ; ++nj)
                acc[mi][nj] = __builtin_amdgcn_mfma_f32_16x16x32_bf16(
                    bfr[nj], af[mi], acc[mi][nj], 0, 0, 0);
        __syncthreads();
    }
    int colb = w * NJ * 16 + quad * 4;
#pragma unroll
    for (int mi = 0; mi < 4; ++mi) {
        size_t rowb = (size_t)(m0 + mi * 16 + m16) * N;
#pragma unroll
        for (int nj = 0; nj < NJ; ++nj) {
            float4 bv = *(const float4*)(bias + colb + nj * 16);
            float v0 = acc[mi][nj][0] + bv.x; v0 = v0 > 0.f ? v0 : 0.01f * v0;
            float v1 = acc[mi][nj][1] + bv.y; v1 = v1 > 0.f ? v1 : 0.01f * v1;
            float v2 = acc[mi][nj][2] + bv.z; v2 = v2 > 0.f ? v2 : 0.01f * v2;
            float v3 = acc[mi][nj][3] + bv.w; v3 = v3 > 0.f ? v3 : 0.01f * v3;
            ushort4 o = { f2bf(v0), f2bf(v1), f2bf(v2), f2bf(v3) };
            *(ushort4*)(U + rowb + colb + nj * 16) = o;
        }
    }
}

// ------------- Chunk-parallel scan, interleaved (re,im) packing -------------
__global__ __launch_bounds__(512) void scan2_k(
    const unsigned short* __restrict__ bu, unsigned short* __restrict__ xs,
    const float* __restrict__ dones,
    const float* __restrict__ h0re, const float* __restrict__ h0im,
    const float* __restrict__ lamre, const float* __restrict__ lamim,
    const float* __restrict__ lstep,
    float* __restrict__ outre, float* __restrict__ outim)
{
    __shared__ float sdone[TT];
    __shared__ float4 ssum[8][64];
    __shared__ float2 shin[8][64];
    int tid = threadIdx.x;
    int b  = blockIdx.x >> 1;
    int ph = blockIdx.x & 1;
    int chunk = tid >> 6, pl = tid & 63;
    int p = ph * 64 + pl;
    sdone[tid] = dones[tid * BB + b];
    float lr = lamre[p], li = lamim[p];
    float st = expf(lstep[p]);
    float er = expf(lr * st);
    float ar = er * cosf(li * st);
    float ai = er * sinf(li * st);
    __syncthreads();

    int t0 = chunk * 64;
    unsigned buf[64];
    float Ar = 1.f, Ai = 0.f, br = 0.f, bi = 0.f;
#pragma unroll
    for (int j = 0; j < 64; ++j) {
        size_t off = ((size_t)(t0 + j) * BB + b) * 256 + 2 * p;
        unsigned v = *(const unsigned*)(bu + off);
        buf[j] = v;
        float bur = bf2f((unsigned short)(v & 0xFFFFu));
        float bui = bf2f((unsigned short)(v >> 16));
        if (sdone[t0 + j] != 0.f) {
            Ar = 0.f; Ai = 0.f; br = bur; bi = bui;
        } else {
            float nAr = ar * Ar - ai * Ai;
            float nAi = ar * Ai + ai * Ar;
            float nbr = fmaf(ar, br, fmaf(-ai, bi, bur));
            float nbi = fmaf(ar, bi, fmaf(ai, br, bui));
            Ar = nAr; Ai = nAi; br = nbr; bi = nbi;
        }
    }
    ssum[chunk][pl] = float4{Ar, Ai, br, bi};
    __syncthreads();
    if (tid < 64) {
        int gid = b * 128 + p;
        float hr = h0re[gid], hi = h0im[gid];
#pragma unroll
        for (int c = 0; c < 8; ++c) {
            shin[c][pl] = float2{hr, hi};
            float4 s = ssum[c][pl];
            float nhr = fmaf(s.x, hr, fmaf(-s.y, hi, s.z));
            float nhi = fmaf(s.x, hi, fmaf(s.y, hr, s.w));
            hr = nhr; hi = nhi;
        }
        outre[gid] = hr; outim[gid] = hi;
    }
    __syncthreads();
    float hr = shin[chunk][pl].x, hi = shin[chunk][pl].y;
#pragma unroll
    for (int j = 0; j < 64; ++j) {
        unsigned v = buf[j];
        float bur = bf2f((unsigned short)(v & 0xFFFFu));
        float bui = bf2f((unsigned short)(v >> 16));
        float nr, ni;
        if (sdone[t0 + j] != 0.f) { nr = bur; ni = bui; }
        else {
            nr = fmaf(ar, hr, fmaf(-ai, hi, bur));
            ni = fmaf(ar, hi, fmaf(ai, hr, bui));
        }
        hr = nr; hi = ni;
        size_t off = ((size_t)(t0 + j) * BB + b) * 256 + 2 * p;
        *(unsigned*)(xs + off) = ((unsigned)f2bf(ni) << 16) | f2bf(nr);
    }
}

// -- Precompute B_barT (interleaved n: 2p/2p+1) and CcatT (interleaved k) ----
__global__ __launch_bounds__(256) void prep_k(
    const float* __restrict__ Br, const float* __restrict__ Bi,
    const float* __restrict__ Cr, const float* __restrict__ Ci,
    const float* __restrict__ Lr, const float* __restrict__ Li,
    const float* __restrict__ ls, unsigned short* bbarT, unsigned short* ccatT)
{
    int gid = blockIdx.x * 256 + threadIdx.x;   // L*P*H = 131072
    int l = gid >> 15;
    int rem = gid & 32767;
    int p = rem >> 8;
    int h = rem & 255;
    float lr = Lr[l * PD + p], li = Li[l * PD + p];
    float st = expf(ls[l * PD + p]);
    float er = expf(lr * st);
    float lbr = er * cosf(li * st);
    float lbi = er * sinf(li * st);
    float nr = lbr - 1.f, ni = lbi;
    float den = lr * lr + li * li;
    float fr = (nr * lr + ni * li) / den;
    float fi = (ni * lr - nr * li) / den;
    float bre = Br[(size_t)(l * PD + p) * HD + h];
    float bim = Bi[(size_t)(l * PD + p) * HD + h];
    size_t lb = (size_t)l * 65536;
    bbarT[lb + (size_t)(2 * p) * 256 + h]     = f2bf(fr * bre - fi * bim);
    bbarT[lb + (size_t)(2 * p + 1) * 256 + h] = f2bf(fr * bim + fi * bre);
    float cre = Cr[(size_t)(l * HD + h) * PD + p];
    float cim = Ci[(size_t)(l * HD + h) * PD + p];
    ccatT[lb + (size_t)h * 256 + 2 * p]     = f2bf(2.f * cre);
    ccatT[lb + (size_t)h * 256 + 2 * p + 1] = f2bf(-2.f * cim);
}

// -------- transpose+convert: in f32 [K][N] -> out bf16 [N][K] ---------------
__global__ __launch_bounds__(256) void tcvt_k(const float* __restrict__ in,
    unsigned short* __restrict__ out, int K, int N)
{
    int gid = blockIdx.x * 256 + threadIdx.x;
    if (gid >= K * N) return;
    int k = gid / N, n = gid - k * N;
    out[(size_t)n * K + k] = f2bf(in[gid]);
}

// ---------------- Final heads: wave per row -> out[row*9 + ...] -------------
__global__ __launch_bounds__(256) void head_k(
    const unsigned short* __restrict__ am2, const unsigned short* __restrict__ v2,
    const float* __restrict__ adW, const float* __restrict__ adb,
    const float* __restrict__ lstd,
    const float* __restrict__ vdW, const float* __restrict__ vdb,
    float* out)
{
    int wid = threadIdx.x >> 6, lane = threadIdx.x & 63;
    size_t row = (size_t)blockIdx.x * 4 + wid;
    float a1 = bf2f(am2[row * 128 + lane]);
    float a2 = bf2f(am2[row * 128 + 64 + lane]);
    float w1 = bf2f(v2[row * 128 + lane]);
    float w2 = bf2f(v2[row * 128 + 64 + lane]);
    float vals[5];
#pragma unroll
    for (int a = 0; a < 4; ++a)
        vals[a] = a1 * adW[lane * 4 + a] + a2 * adW[(lane + 64) * 4 + a];
    vals[4] = w1 * vdW[lane] + w2 * vdW[64 + lane];
#pragma unroll
    for (int off = 32; off; off >>= 1)
#pragma unroll
        for (int k = 0; k < 5; ++k) vals[k] += __shfl_xor(vals[k], off);
    if (lane == 0) {
        size_t o = row * 9;
#pragma unroll
        for (int a = 0; a < 4; ++a) out[o + a] = vals[a] + adb[a];
#pragma unroll
        for (int a = 0; a < 4; ++a) out[o + 4 + a] = expf(lstd[a]);
        out[o + 8] = vals[4] + vdb[0];
    }
}

extern "C" void kernel_launch(void* const* d_in, const int* in_sizes, int n_in,
                              void* d_out, int out_size, void* d_ws, size_t ws_size,
                              hipStream_t stream) {
    (void)in_sizes; (void)n_in; (void)out_size; (void)ws_size;
    const float* obs     = (const float*)d_in[0];
    const float* dones   = (const float*)d_in[1];
    const float* hre     = (const float*)d_in[2];
    const float* him     = (const float*)d_in[3];
    const float* enc0_W  = (const float*)d_in[4];
    const float* enc0_b  = (const float*)d_in[5];
    const float* enc1_W  = (const float*)d_in[6];
    const float* enc1_b  = (const float*)d_in[7];
    const float* nsc     = (const float*)d_in[8];
    const float* nbi     = (const float*)d_in[9];
    const float* Lre     = (const float*)d_in[10];
    const float* Lim     = (const float*)d_in[11];
    const float* B_re    = (const float*)d_in[12];
    const float* B_im    = (const float*)d_in[13];
    const float* C_re    = (const float*)d_in[14];
    const float* C_im    = (const float*)d_in[15];
    const float* Dv      = (const float*)d_in[16];
    const float* lstep   = (const float*)d_in[17];
    const float* glu_W   = (const float*)d_in[18];
    const float* glu_b   = (const float*)d_in[19];
    const float* ab0_W   = (const float*)d_in[20];
    const float* ab0_b   = (const float*)d_in[21];
    const float* ab1_W   = (const float*)d_in[22];
    const float* ab1_b   = (const float*)d_in[23];
    const float* adec_W  = (const float*)d_in[24];
    const float* adec_b  = (const float*)d_in[25];
    const float* log_std = (const float*)d_in[26];
    const float* vb0_W   = (const float*)d_in[27];
    const float* vb0_b   = (const float*)d_in[28];
    const float* vb1_W   = (const float*)d_in[29];
    const float* vb1_b   = (const float*)d_in[30];
    const float* vdec_W  = (const float*)d_in[31];
    const float* vdec_b  = (const float*)d_in[32];

    const size_t MB = (size_t)1 << 20;
    char* wsb = (char*)d_ws;
    unsigned short* XS    = (unsigned short*)(wsb);              // 32MB (per-layer xs)
    unsigned short* AM1   = (unsigned short*)(wsb);              // 16MB (heads)
    unsigned short* V1    = (unsigned short*)(wsb + 16 * MB);    // 16MB (heads)
    unsigned short* AM2   = (unsigned short*)(wsb + 32 * MB);    // 16MB (heads)
    unsigned short* V2    = (unsigned short*)(wsb + 48 * MB);    // 16MB (heads)
    unsigned short* U1    = (unsigned short*)(wsb + 64 * MB);    // 16MB (enc0 out)
    unsigned short* X     = (unsigned short*)(wsb + 96 * MB);    // 32MB residual bf16
    unsigned short* U     = (unsigned short*)(wsb + 128 * MB);   // 32MB (u / z)
    unsigned short* BU    = (unsigned short*)(wsb + 160 * MB);   // 32MB (Bu)
    char* wgt = wsb + 192 * MB;
    unsigned short* BBART = (unsigned short*)(wgt);              // 512KB
    unsigned short* CCATT = (unsigned short*)(wgt + 512 * 1024);
    unsigned short* GLUT  = (unsigned short*)(wgt + 1024 * 1024);
    unsigned short* E0T   = (unsigned short*)(wgt + 1536 * 1024);
    unsigned short* E1T   = (unsigned short*)(wgt + 1664 * 1024);
    unsigned short* AB0T  = (unsigned short*)(wgt + 1728 * 1024);
    unsigned short* AB1T  = (unsigned short*)(wgt + 1792 * 1024);
    unsigned short* VB0T  = (unsigned short*)(wgt + 1824 * 1024);
    unsigned short* VB1T  = (unsigned short*)(wgt + 1888 * 1024);

    float* out   = (float*)d_out;
    float* outre = out + (size_t)NTB * 9;
    float* outim = outre + LD * BB * PD;

    // ---- weight prep ----
    prep_k<<<512, 256, 0, stream>>>(B_re, B_im, C_re, C_im, Lre, Lim, lstep, BBART, CCATT);
    tcvt_k<<<256, 256, 0, stream>>>(enc0_W, E0T, 512, 128);
    tcvt_k<<<128, 256, 0, stream>>>(enc1_W, E1T, 128, 256);
    for (int l = 0; l < LD; ++l)
        tcvt_k<<<256, 256, 0, stream>>>(glu_W + (size_t)l * 65536, GLUT + (size_t)l * 65536, 256, 256);
    tcvt_k<<<128, 256, 0, stream>>>(ab0_W, AB0T, 256, 128);
    tcvt_k<<<64, 256, 0, stream>>>(ab1_W, AB1T, 128, 128);
    tcvt_k<<<128, 256, 0, stream>>>(vb0_W, VB0T, 256, 128);
    tcvt_k<<<64, 256, 0, stream>>>(vb1_W, VB1T, 128, 128);

    // ---- encoder ----
    mgemm_obs<<<1024, 256, 0, stream>>>(obs, E0T, U1, enc0_b);
    // enc1 fused: X = leaky(U1@E1+b), U = LN_0(X)
    mgemm2<0, 4><<<1024, 256, 0, stream>>>(U1, E1T, 128, enc1_b, nsc, nbi, nullptr, X, U, 1);

    // ---- S5 layers ----
    for (int l = 0; l < LD; ++l) {
        mgemm2<1, 4><<<1024, 256, 0, stream>>>(U, BBART + (size_t)l * 65536, 256,
                                               nullptr, nullptr, nullptr, nullptr, nullptr, BU, 0);
        scan2_k<<<256, 512, 0, stream>>>(BU, XS, dones, hre + l * BB * PD, him + l * BB * PD,
                                         Lre + l * PD, Lim + l * PD, lstep + l * PD,
                                         outre + l * BB * PD, outim + l * BB * PD);
        // z = gelu(LN_l(xs@C + D*u))   (in-place U: aux1=U read, U written)
        mgemm2<2, 4><<<1024, 256, 0, stream>>>(XS, CCATT + (size_t)l * 65536, 256,
                                               Dv + l * HD, nsc + l * HD, nbi + l * HD, U, nullptr, U, 1);
        // x += z*sigmoid(z@W+b); u_next = LN_{l+1}(x)  (skip LN on last layer)
        const float* nsc2 = nsc + ((l + 1 < LD) ? (l + 1) * HD : 0);
        const float* nbi2 = nbi + ((l + 1 < LD) ? (l + 1) * HD : 0);
        mgemm2<3, 4><<<1024, 256, 0, stream>>>(U, GLUT + (size_t)l * 65536, 256,
                                               glu_b + l * HD, nsc2, nbi2, U, X, U, (l + 1 < LD) ? 1 : 0);
    }

    // ---- heads ----
    mgemm2<4, 2><<<1024, 256, 0, stream>>>(X, AB0T, 256, ab0_b, nullptr, nullptr, nullptr, nullptr, AM1, 0);
    mgemm2<4, 2><<<1024, 256, 0, stream>>>(AM1, AB1T, 128, ab1_b, nullptr, nullptr, nullptr, nullptr, AM2, 0);
    mgemm2<4, 2><<<1024, 256, 0, stream>>>(X, VB0T, 256, vb0_b, nullptr, nullptr, nullptr, nullptr, V1, 0);
    mgemm2<4, 2><<<1024, 256, 0, stream>>>(V1, VB1T, 128, vb1_b, nullptr, nullptr, nullptr, nullptr, V2, 0);
    head_k<<<NTB / 4, 256, 0, stream>>>(AM2, V2, adec_W, adec_b, log_std, vdec_W, vdec_b, out);
}